// Round 1
// baseline (693.521 us; speedup 1.0000x reference)
//
#include <hip/hip_runtime.h>

#define NB 8192
#define NS 50
#define ND 128
#define NP 16
#define NU 50000

// ---------------- inverse map ----------------
__global__ void k_init_map(int* __restrict__ map) {
    int i = blockIdx.x * blockDim.x + threadIdx.x;
    if (i < NU) map[i] = -1;
}

__global__ void k_scatter_map(const int* __restrict__ user_idx, int* __restrict__ map) {
    int b = blockIdx.x * blockDim.x + threadIdx.x;
    if (b < NB) map[user_idx[b]] = b;
}

// ---------------- per-batch update vector ----------------
// one 128-thread block per batch element b
__global__ void k_upd(const float* __restrict__ features,
                      const float* __restrict__ mask,
                      float* __restrict__ upd) {
    int b = blockIdx.x;
    int d = threadIdx.x;                 // 0..127

    __shared__ float smask[NS];
    __shared__ float red[ND];

    if (d < NS) smask[d] = mask[(size_t)b * NS + d];
    __syncthreads();

    float msum = 0.f;
#pragma unroll
    for (int s = 0; s < NS; ++s) msum += smask[s];

    const float* f = features + (size_t)b * NS * ND + d;
    float acc = 0.f;
#pragma unroll 5
    for (int s = 0; s < NS; ++s) acc += f[(size_t)s * ND] * smask[s];

    float u = acc / fmaxf(msum, 1e-6f);

    // L2 norm across the 128 dims
    red[d] = u * u;
    __syncthreads();
    for (int off = 64; off > 0; off >>= 1) {
        if (d < off) red[d] += red[d + off];
        __syncthreads();
    }
    float norm = sqrtf(red[0]);
    u = u / fmaxf(norm, 1e-12f);

    upd[(size_t)b * ND + d] = u;
}

// ---------------- shared prototype update ----------------
// single block, 512 threads
__global__ void k_shared(const float* __restrict__ upd,
                         const float* __restrict__ shared_in,
                         float* __restrict__ shared_out) {
    int tid = threadIdx.x;
    int d = tid & 127;
    int q = tid >> 7;  // 0..3

    float s = 0.f;
    for (int b = q; b < NB; b += 4) s += upd[(size_t)b * ND + d];

    __shared__ float part[4][ND];
    __shared__ float meanbuf[ND];
    __shared__ float snorm;
    part[q][d] = s;
    __syncthreads();

    if (q == 0) {
        float tot = part[0][d] + part[1][d] + part[2][d] + part[3][d];
        meanbuf[d] = tot / (float)NB;
    }
    __syncthreads();

    if (tid == 0) {
        float ss = 0.f;
        for (int i = 0; i < ND; ++i) ss += meanbuf[i] * meanbuf[i];
        snorm = sqrtf(ss);
    }
    __syncthreads();

    float inv = 1.0f / fmaxf(snorm, 1e-12f);
    // 2048 output elements, 512 threads -> 4 each
    for (int i = tid; i < NP * ND; i += 512) {
        float su = meanbuf[i & 127] * inv;
        shared_out[i] = 0.9f * shared_in[i] + 0.1f * su;
    }
}

// ---------------- big copy / blend ----------------
// one float4 (4 consecutive d) per thread
__global__ void k_blend(const float* __restrict__ proto,
                        const float* __restrict__ ic,
                        const int* __restrict__ map,
                        const float* __restrict__ upd,
                        float* __restrict__ out) {
    size_t g = (size_t)blockIdx.x * blockDim.x + threadIdx.x;  // float4 index
    const size_t total = (size_t)NU * NP * ND / 4;             // 25,600,000
    if (g >= total) return;

    float4 v = ((const float4*)proto)[g];
    int u = (int)(g >> 9);        // / (16*128/4 = 512)
    int rem = (int)(g & 511);
    int b = map[u];
    if (b >= 0) {
        float icv = ic[u];
        float m = fminf(fmaxf(0.9f + icv * 0.001f, 0.9f), 0.99f);
        float om = 1.0f - m;
        float4 up = ((const float4*)upd)[(size_t)b * 32 + (rem & 31)];
        v.x = m * v.x + om * up.x;
        v.y = m * v.y + om * up.y;
        v.z = m * v.z + om * up.z;
        v.w = m * v.w + om * up.w;
    }
    ((float4*)out)[g] = v;
}

// ---------------- interaction count ----------------
__global__ void k_ic_copy(const float* __restrict__ ic, float* __restrict__ out) {
    int i = blockIdx.x * blockDim.x + threadIdx.x;
    if (i < NU) out[i] = ic[i];
}

__global__ void k_ic_add(const int* __restrict__ user_idx, float* __restrict__ out) {
    int b = blockIdx.x * blockDim.x + threadIdx.x;
    if (b < NB) atomicAdd(&out[user_idx[b]], 1.0f);
}

extern "C" void kernel_launch(void* const* d_in, const int* in_sizes, int n_in,
                              void* d_out, int out_size, void* d_ws, size_t ws_size,
                              hipStream_t stream) {
    const float* user_prototypes   = (const float*)d_in[0];  // [NU, NP, ND]
    const float* shared_prototypes = (const float*)d_in[1];  // [1, NP, ND]
    const float* interaction_count = (const float*)d_in[2];  // [NU]
    const float* features          = (const float*)d_in[3];  // [NB, NS, ND]
    const float* success_mask      = (const float*)d_in[4];  // [NB, NS]
    const int*   user_idx          = (const int*)d_in[5];    // [NB]

    float* out_proto  = (float*)d_out;                         // NU*NP*ND
    float* out_shared = out_proto + (size_t)NU * NP * ND;      // NP*ND
    float* out_ic     = out_shared + NP * ND;                  // NU

    // workspace layout
    int*   map = (int*)d_ws;                                   // NU ints (200 KB)
    float* upd = (float*)((char*)d_ws + 200704);               // NB*ND floats (4 MB), 16B-aligned

    k_init_map<<<(NU + 255) / 256, 256, 0, stream>>>(map);
    k_scatter_map<<<(NB + 255) / 256, 256, 0, stream>>>(user_idx, map);

    k_upd<<<NB, ND, 0, stream>>>(features, success_mask, upd);

    k_shared<<<1, 512, 0, stream>>>(upd, shared_prototypes, out_shared);

    const size_t total4 = (size_t)NU * NP * ND / 4;
    k_blend<<<(int)((total4 + 255) / 256), 256, 0, stream>>>(
        user_prototypes, interaction_count, map, upd, out_proto);

    k_ic_copy<<<(NU + 255) / 256, 256, 0, stream>>>(interaction_count, out_ic);
    k_ic_add<<<(NB + 255) / 256, 256, 0, stream>>>(user_idx, out_ic);
}

// Round 2
// 220.902 us; speedup vs baseline: 3.1395x; 3.1395x over previous
//
#include <hip/hip_runtime.h>

#define NB 8192
#define NS 50
#define ND 128
#define NP 16
#define NU 50000
#define NRED 64   // stage-1 reduction blocks

// ---------------- inverse map ----------------
__global__ void k_init_map(int* __restrict__ map) {
    int i = blockIdx.x * blockDim.x + threadIdx.x;
    if (i < NU) map[i] = -1;
}

__global__ void k_scatter_map(const int* __restrict__ user_idx, int* __restrict__ map) {
    int b = blockIdx.x * blockDim.x + threadIdx.x;
    if (b < NB) map[user_idx[b]] = b;
}

// ---------------- per-batch update vector ----------------
// one 128-thread block per batch element b
__global__ void k_upd(const float* __restrict__ features,
                      const float* __restrict__ mask,
                      float* __restrict__ upd) {
    int b = blockIdx.x;
    int d = threadIdx.x;                 // 0..127

    __shared__ float smask[NS];
    __shared__ float red[ND];

    if (d < NS) smask[d] = mask[(size_t)b * NS + d];
    __syncthreads();

    float msum = 0.f;
#pragma unroll
    for (int s = 0; s < NS; ++s) msum += smask[s];

    const float* f = features + (size_t)b * NS * ND + d;
    float acc = 0.f;
#pragma unroll 5
    for (int s = 0; s < NS; ++s) acc += f[(size_t)s * ND] * smask[s];

    float u = acc / fmaxf(msum, 1e-6f);

    // L2 norm across the 128 dims
    red[d] = u * u;
    __syncthreads();
    for (int off = 64; off > 0; off >>= 1) {
        if (d < off) red[d] += red[d + off];
        __syncthreads();
    }
    float norm = sqrtf(red[0]);
    u = u / fmaxf(norm, 1e-12f);

    upd[(size_t)b * ND + d] = u;
}

// ---------------- stage-1 column sum over B ----------------
// NRED blocks x 256 threads; block i sums rows [i*(NB/NRED), (i+1)*(NB/NRED))
__global__ void k_colsum(const float* __restrict__ upd, float* __restrict__ part) {
    int blk = blockIdx.x;
    int t = threadIdx.x;
    int d = t & 127;       // column
    int h = t >> 7;        // 0 or 1

    const int rows = NB / NRED;          // 128
    int r0 = blk * rows;

    float s = 0.f;
    for (int r = r0 + h; r < r0 + rows; r += 2)
        s += upd[(size_t)r * ND + d];

    __shared__ float red[2][ND];
    red[h][d] = s;
    __syncthreads();
    if (h == 0)
        part[(size_t)blk * ND + d] = red[0][d] + red[1][d];
}

// ---------------- stage-2: mean, normalize, blend shared ----------------
// single small block, 128 threads
__global__ void k_shared_final(const float* __restrict__ part,
                               const float* __restrict__ shared_in,
                               float* __restrict__ shared_out) {
    int d = threadIdx.x;   // 0..127

    float tot = 0.f;
#pragma unroll
    for (int j = 0; j < NRED; ++j) tot += part[(size_t)j * ND + d];
    float mean = tot / (float)NB;

    __shared__ float red[ND];
    red[d] = mean * mean;
    __syncthreads();
    for (int off = 64; off > 0; off >>= 1) {
        if (d < off) red[d] += red[d + off];
        __syncthreads();
    }
    float inv = 1.0f / fmaxf(sqrtf(red[0]), 1e-12f);
    float su = mean * inv;

#pragma unroll
    for (int p = 0; p < NP; ++p)
        shared_out[p * ND + d] = 0.9f * shared_in[p * ND + d] + 0.1f * su;
}

// ---------------- big copy / blend ----------------
// one float4 (4 consecutive d) per thread
__global__ void k_blend(const float* __restrict__ proto,
                        const float* __restrict__ ic,
                        const int* __restrict__ map,
                        const float* __restrict__ upd,
                        float* __restrict__ out) {
    size_t g = (size_t)blockIdx.x * blockDim.x + threadIdx.x;  // float4 index
    const size_t total = (size_t)NU * NP * ND / 4;             // 25,600,000
    if (g >= total) return;

    float4 v = ((const float4*)proto)[g];
    int u = (int)(g >> 9);        // / (16*128/4 = 512)
    int rem = (int)(g & 511);
    int b = map[u];
    if (b >= 0) {
        float icv = ic[u];
        float m = fminf(fmaxf(0.9f + icv * 0.001f, 0.9f), 0.99f);
        float om = 1.0f - m;
        float4 up = ((const float4*)upd)[(size_t)b * 32 + (rem & 31)];
        v.x = m * v.x + om * up.x;
        v.y = m * v.y + om * up.y;
        v.z = m * v.z + om * up.z;
        v.w = m * v.w + om * up.w;
    }
    ((float4*)out)[g] = v;
}

// ---------------- interaction count ----------------
__global__ void k_ic_copy(const float* __restrict__ ic, float* __restrict__ out) {
    int i = blockIdx.x * blockDim.x + threadIdx.x;
    if (i < NU) out[i] = ic[i];
}

__global__ void k_ic_add(const int* __restrict__ user_idx, float* __restrict__ out) {
    int b = blockIdx.x * blockDim.x + threadIdx.x;
    if (b < NB) atomicAdd(&out[user_idx[b]], 1.0f);
}

extern "C" void kernel_launch(void* const* d_in, const int* in_sizes, int n_in,
                              void* d_out, int out_size, void* d_ws, size_t ws_size,
                              hipStream_t stream) {
    const float* user_prototypes   = (const float*)d_in[0];  // [NU, NP, ND]
    const float* shared_prototypes = (const float*)d_in[1];  // [1, NP, ND]
    const float* interaction_count = (const float*)d_in[2];  // [NU]
    const float* features          = (const float*)d_in[3];  // [NB, NS, ND]
    const float* success_mask      = (const float*)d_in[4];  // [NB, NS]
    const int*   user_idx          = (const int*)d_in[5];    // [NB]

    float* out_proto  = (float*)d_out;                         // NU*NP*ND
    float* out_shared = out_proto + (size_t)NU * NP * ND;      // NP*ND
    float* out_ic     = out_shared + NP * ND;                  // NU

    // workspace layout (16B aligned chunks)
    int*   map  = (int*)d_ws;                                  // NU ints (200 KB)
    float* upd  = (float*)((char*)d_ws + 200704);              // NB*ND floats (4 MB)
    float* part = upd + (size_t)NB * ND;                       // NRED*ND floats (32 KB)

    k_init_map<<<(NU + 255) / 256, 256, 0, stream>>>(map);
    k_scatter_map<<<(NB + 255) / 256, 256, 0, stream>>>(user_idx, map);

    k_upd<<<NB, ND, 0, stream>>>(features, success_mask, upd);

    k_colsum<<<NRED, 256, 0, stream>>>(upd, part);
    k_shared_final<<<1, ND, 0, stream>>>(part, shared_prototypes, out_shared);

    const size_t total4 = (size_t)NU * NP * ND / 4;
    k_blend<<<(int)((total4 + 255) / 256), 256, 0, stream>>>(
        user_prototypes, interaction_count, map, upd, out_proto);

    k_ic_copy<<<(NU + 255) / 256, 256, 0, stream>>>(interaction_count, out_ic);
    k_ic_add<<<(NB + 255) / 256, 256, 0, stream>>>(user_idx, out_ic);
}